// Round 4
// baseline (451.152 us; speedup 1.0000x reference)
//
#include <hip/hip_runtime.h>

typedef unsigned short u16;
typedef __bf16 bf16x8_t __attribute__((ext_vector_type(8)));
typedef float f32x4_t __attribute__((ext_vector_type(4)));

#define T_SEQ 4096
#define EMB 512
#define NH 8
#define NKV 2
#define HD 64

__device__ __forceinline__ float bf2f(u16 h) {
    union { unsigned u; float f; } x; x.u = ((unsigned)h) << 16; return x.f;
}
__device__ __forceinline__ u16 f2bf(float f) {
    union { float f; unsigned u; } x; x.f = f;
    unsigned r = x.u + 0x7FFFu + ((x.u >> 16) & 1u);
    return (u16)(r >> 16);
}

// ------------- weight transpose + cast: W[K][N] (f32) -> WT[N][K] (bf16) -------------
__global__ void transpose_kernel(const float* __restrict__ W, u16* __restrict__ WT,
                                 int K, int N) {
    int i = blockIdx.x * 256 + threadIdx.x;
    if (i < K * N) {
        int n = i / K;
        int k = i - n * K;
        WT[i] = f2bf(W[(size_t)k * N + n]);
    }
}

// ------------- x cast: f32 -> bf16, 4 elems/thread -------------
__global__ void cvt_kernel(const float* __restrict__ in, u16* __restrict__ out, int n4) {
    int i = blockIdx.x * 256 + threadIdx.x;
    if (i < n4) {
        float4 v = *reinterpret_cast<const float4*>(in + (size_t)i * 4);
        u16 o[4] = { f2bf(v.x), f2bf(v.y), f2bf(v.z), f2bf(v.w) };
        *reinterpret_cast<uint2*>(out + (size_t)i * 4) = *reinterpret_cast<uint2*>(o);
    }
}

// ------------- RoPE tables: cos/sin[t][j], j<32, fp32 (double trig ~= np ref) -------------
__global__ void rope_table_kernel(float* __restrict__ cost, float* __restrict__ sint) {
    int i = blockIdx.x * 256 + threadIdx.x;   // T_SEQ*32 total
    int t = i >> 5, j = i & 31;
    double invf = pow(1.0e6, -(double)j / 32.0);
    double ang = (double)t * invf;
    cost[i] = (float)cos(ang);
    sint[i] = (float)sin(ang);
}

// ---------------- GEMM: C[M,N] = A[M,K](bf16) @ Bt[N,K](bf16)^T ----------------
// EPI=0: fp32 store to C.  EPI=1: bias + RoPE + scale-q(incl log2e) + scatter q/k + V transposed.
template <int EPI>
__global__ __launch_bounds__(256)
void gemm_kernel(const u16* __restrict__ A, const u16* __restrict__ Bt, int K,
                 float* __restrict__ C, int N,
                 const float* __restrict__ bq, const float* __restrict__ bk,
                 const float* __restrict__ bv,
                 const float* __restrict__ cost, const float* __restrict__ sint,
                 u16* __restrict__ qw, u16* __restrict__ kw, u16* __restrict__ vt)
{
    __shared__ __align__(16) u16 As[128][72];
    __shared__ __align__(16) u16 Bs[128][72];

    const int tid  = threadIdx.x;
    const int lane = tid & 63, wave = tid >> 6;
    const int wr = wave >> 1, wc = wave & 1;
    const int tm = blockIdx.x, tn = blockIdx.y;
    const int lrow = lane & 15, lgrp = lane >> 4;

    f32x4_t acc[4][4];
#pragma unroll
    for (int i = 0; i < 4; ++i)
#pragma unroll
        for (int j = 0; j < 4; ++j) acc[i][j] = (f32x4_t){0.f, 0.f, 0.f, 0.f};

    for (int k0 = 0; k0 < K; k0 += 64) {
        __syncthreads();
        {
            const int r0 = tid >> 3;
            const int ko = (tid & 7) * 8;
#pragma unroll
            for (int rr = 0; rr < 4; ++rr) {
                int row = r0 + rr * 32;
                uint4 va = *reinterpret_cast<const uint4*>(A + (size_t)(tm * 128 + row) * K + k0 + ko);
                *reinterpret_cast<uint4*>(&As[row][ko]) = va;
                uint4 vb = *reinterpret_cast<const uint4*>(Bt + (size_t)(tn * 128 + row) * K + k0 + ko);
                *reinterpret_cast<uint4*>(&Bs[row][ko]) = vb;
            }
        }
        __syncthreads();
#pragma unroll
        for (int kc = 0; kc < 2; ++kc) {
            bf16x8_t af[4], bf[4];
#pragma unroll
            for (int mb = 0; mb < 4; ++mb)
                af[mb] = *reinterpret_cast<const bf16x8_t*>(&As[wr * 64 + mb * 16 + lrow][kc * 32 + lgrp * 8]);
#pragma unroll
            for (int nb = 0; nb < 4; ++nb)
                bf[nb] = *reinterpret_cast<const bf16x8_t*>(&Bs[wc * 64 + nb * 16 + lrow][kc * 32 + lgrp * 8]);
#pragma unroll
            for (int mb = 0; mb < 4; ++mb)
#pragma unroll
                for (int nb = 0; nb < 4; ++nb)
                    acc[mb][nb] = __builtin_amdgcn_mfma_f32_16x16x32_bf16(af[mb], bf[nb], acc[mb][nb], 0, 0, 0);
        }
    }

    if (EPI == 0) {
#pragma unroll
        for (int mb = 0; mb < 4; ++mb)
#pragma unroll
            for (int nb = 0; nb < 4; ++nb)
#pragma unroll
                for (int r = 0; r < 4; ++r) {
                    int row = tm * 128 + wr * 64 + mb * 16 + lgrp * 4 + r;
                    int col = tn * 128 + wc * 64 + nb * 16 + lrow;
                    C[(size_t)row * N + col] = acc[mb][nb][r];
                }
    } else {
        const float QSC = 0.125f * 1.44269504088896f;   // head_dim^-0.5 * log2(e)
#pragma unroll
        for (int mb = 0; mb < 4; ++mb)
#pragma unroll
            for (int r = 0; r < 4; ++r) {
                int grow = tm * 128 + wr * 64 + mb * 16 + lgrp * 4 + r;
                int b = grow >> 12, t = grow & 4095;
#pragma unroll
                for (int nb = 0; nb < 2; ++nb) {
                    int n = tn * 128 + wc * 64 + nb * 16 + lrow;
                    int j = n & 63;
                    float c0 = acc[mb][nb][r];
                    float c1 = acc[mb][nb + 2][r];
                    if (n < 512) {               // Q (softmax runs in exp2 domain)
                        c0 += bq[n]; c1 += bq[n + 32];
                        float cs = cost[t * 32 + j], sn = sint[t * 32 + j];
                        float r0 = (c0 * cs - c1 * sn) * QSC;
                        float r1 = (c1 * cs + c0 * sn) * QSC;
                        int h = n >> 6;
                        size_t base = ((size_t)(b * NH + h) * T_SEQ + t) * HD;
                        qw[base + j]      = f2bf(r0);
                        qw[base + j + 32] = f2bf(r1);
                    } else if (n < 640) {        // K
                        int nn = n - 512;
                        c0 += bk[nn]; c1 += bk[nn + 32];
                        float cs = cost[t * 32 + j], sn = sint[t * 32 + j];
                        float r0 = c0 * cs - c1 * sn;
                        float r1 = c1 * cs + c0 * sn;
                        int hk2 = nn >> 6;
                        size_t base = ((size_t)(b * NKV + hk2) * T_SEQ + t) * HD;
                        kw[base + j]      = f2bf(r0);
                        kw[base + j + 32] = f2bf(r1);
                    } else {                     // V -> transposed vt[b][hk][d][t]
                        int nn = n - 640;
                        c0 += bv[nn]; c1 += bv[nn + 32];
                        int hv = nn >> 6;
                        size_t base = (size_t)(b * NKV + hv) * HD * T_SEQ;
                        vt[base + (size_t)j * T_SEQ + t]        = f2bf(c0);
                        vt[base + (size_t)(j + 32) * T_SEQ + t] = f2bf(c1);
                    }
                }
            }
    }
}

// ---------------- wave-autonomous causal flash attention ----------------
// grid: (T/64, B*NH), 256 thr = 4 waves, NO __syncthreads, NO K/V LDS staging.
// Each wave owns 16 q-rows; K/V MFMA fragments loaded straight from global (L1/L2-hot).
// LDS only holds wave-private P (transpose between QK^T C-layout and PV A-layout).
__global__ __launch_bounds__(256)
void attn_kernel(const u16* __restrict__ qw, const u16* __restrict__ kw,
                 const u16* __restrict__ vt, u16* __restrict__ ao)
{
    __shared__ __align__(16) __bf16 Ps[4][16][68];   // [wave][qrow][kv+pad]

    const int qt = (gridDim.x - 1) - blockIdx.x;     // worst-first
    const int hdix = blockIdx.y;
    const int b = hdix >> 3, h = hdix & 7, hk = h >> 2;
    const int tid = threadIdx.x, lane = tid & 63, wave = tid >> 6;
    const int lrow = lane & 15, lgrp = lane >> 4;

    const u16* qbase  = qw + ((size_t)(b * NH + h) * T_SEQ + qt * 64) * HD;
    const u16* kbase  = kw + (size_t)(b * NKV + hk) * T_SEQ * HD;
    const u16* vtbase = vt + (size_t)(b * NKV + hk) * HD * T_SEQ;

    // per-lane fragment offsets
    //   K frag (B-op of QK):  K[kb*16+lrow][kc*32+lgrp*8 + j]   (d-contiguous)
    //   V frag (B-op of PV):  vt[db*16+lrow][kt*64 + kc*32+lgrp*8 + j]  (t-contiguous)
    const int klo = lrow * HD + lgrp * 8;            // + kb*16*HD + kc*32 + kt*64*HD
    const int vlo = lrow * T_SEQ + lgrp * 8;         // + db*16*T_SEQ + kc*32 + kt*64

    bf16x8_t qf[2];
#pragma unroll
    for (int kc = 0; kc < 2; ++kc)
        qf[kc] = *reinterpret_cast<const bf16x8_t*>(qbase + (wave * 16 + lrow) * HD + kc * 32 + lgrp * 8);

    float m[4], l[4];
    f32x4_t o[4];
#pragma unroll
    for (int r = 0; r < 4; ++r) { m[r] = -1e30f; l[r] = 0.f; }
#pragma unroll
    for (int d = 0; d < 4; ++d) o[d] = (f32x4_t){0.f, 0.f, 0.f, 0.f};

    for (int kt = 0; kt <= qt; ++kt) {
        // ---- K fragments straight from global ----
        bf16x8_t kf[2][4];
#pragma unroll
        for (int kc = 0; kc < 2; ++kc)
#pragma unroll
            for (int kb = 0; kb < 4; ++kb)
                kf[kc][kb] = *reinterpret_cast<const bf16x8_t*>(
                    kbase + (size_t)kt * 64 * HD + kb * 16 * HD + kc * 32 + klo);
        // ---- V fragments issued now, consumed after softmax (latency hides) ----
        bf16x8_t vf[2][4];
#pragma unroll
        for (int kc = 0; kc < 2; ++kc)
#pragma unroll
            for (int db = 0; db < 4; ++db)
                vf[kc][db] = *reinterpret_cast<const bf16x8_t*>(
                    vtbase + (size_t)db * 16 * T_SEQ + kt * 64 + kc * 32 + vlo);

        // ---- S = q @ k^T ----
        f32x4_t sacc[4];
#pragma unroll
        for (int kb = 0; kb < 4; ++kb) sacc[kb] = (f32x4_t){0.f, 0.f, 0.f, 0.f};
        __builtin_amdgcn_s_setprio(1);
#pragma unroll
        for (int kc = 0; kc < 2; ++kc)
#pragma unroll
            for (int kb = 0; kb < 4; ++kb)
                sacc[kb] = __builtin_amdgcn_mfma_f32_16x16x32_bf16(qf[kc], kf[kc][kb], sacc[kb], 0, 0, 0);
        __builtin_amdgcn_s_setprio(0);

        if (kt == qt) {   // causal mask, diagonal tile only
#pragma unroll
            for (int kb = 0; kb < 4; ++kb)
#pragma unroll
                for (int r = 0; r < 4; ++r) {
                    int qr = wave * 16 + lgrp * 4 + r;
                    int kc2 = kb * 16 + lrow;
                    if (kc2 > qr) sacc[kb][r] = -1e30f;
                }
        }

        // ---- online softmax in exp2 domain (rows live in 16-lane groups) ----
        float al[4];
#pragma unroll
        for (int r = 0; r < 4; ++r) {
            float v = fmaxf(fmaxf(sacc[0][r], sacc[1][r]), fmaxf(sacc[2][r], sacc[3][r]));
#pragma unroll
            for (int off = 1; off < 16; off <<= 1) v = fmaxf(v, __shfl_xor(v, off));
            float mn = fmaxf(m[r], v);
            al[r] = exp2f(m[r] - mn);
            m[r] = mn;
        }
#pragma unroll
        for (int kb = 0; kb < 4; ++kb)
#pragma unroll
            for (int r = 0; r < 4; ++r) sacc[kb][r] = exp2f(sacc[kb][r] - m[r]);   // p in place
#pragma unroll
        for (int r = 0; r < 4; ++r) {
            float v = sacc[0][r] + sacc[1][r] + sacc[2][r] + sacc[3][r];
#pragma unroll
            for (int off = 1; off < 16; off <<= 1) v += __shfl_xor(v, off);
            l[r] = l[r] * al[r] + v;
        }
#pragma unroll
        for (int d = 0; d < 4; ++d)
#pragma unroll
            for (int r = 0; r < 4; ++r) o[d][r] *= al[r];

        // ---- P transpose through wave-private LDS (no barrier) ----
#pragma unroll
        for (int kb = 0; kb < 4; ++kb)
#pragma unroll
            for (int r = 0; r < 4; ++r)
                Ps[wave][lgrp * 4 + r][kb * 16 + lrow] = (__bf16)sacc[kb][r];

        // ---- O += P @ V ----
        __builtin_amdgcn_s_setprio(1);
#pragma unroll
        for (int kc = 0; kc < 2; ++kc) {
            bf16x8_t pf = *reinterpret_cast<const bf16x8_t*>(&Ps[wave][lrow][kc * 32 + lgrp * 8]);
#pragma unroll
            for (int d = 0; d < 4; ++d)
                o[d] = __builtin_amdgcn_mfma_f32_16x16x32_bf16(pf, vf[kc][d], o[d], 0, 0, 0);
        }
        __builtin_amdgcn_s_setprio(0);
    }

    // epilogue: normalize and store [B,T,H*D] (bf16)
#pragma unroll
    for (int d = 0; d < 4; ++d)
#pragma unroll
        for (int r = 0; r < 4; ++r) {
            int t = qt * 64 + wave * 16 + lgrp * 4 + r;
            float inv = 1.0f / l[r];
            ao[((size_t)(b * T_SEQ) + t) * EMB + h * HD + d * 16 + lrow] = f2bf(o[d][r] * inv);
        }
}

// ---------------- launch ----------------
extern "C" void kernel_launch(void* const* d_in, const int* in_sizes, int n_in,
                              void* d_out, int out_size, void* d_ws, size_t ws_size,
                              hipStream_t stream)
{
    const float* x  = (const float*)d_in[0];
    const float* Wq = (const float*)d_in[1];
    const float* bq = (const float*)d_in[2];
    const float* Wk = (const float*)d_in[3];
    const float* bk = (const float*)d_in[4];
    const float* Wv = (const float*)d_in[5];
    const float* bv = (const float*)d_in[6];
    const float* Wo = (const float*)d_in[7];
    float* out = (float*)d_out;

    char* ws = (char*)d_ws;
    u16*   WqkvT = (u16*)(ws);                  // [768][512] bf16
    u16*   WoT   = (u16*)(ws + 786432);         // [512][512] bf16
    float* cost  = (float*)(ws + 1310720);      // [4096][32] f32
    float* sint  = (float*)(ws + 1835008);      // [4096][32] f32
    u16*   xbf   = (u16*)(ws + 2359296);        // [8192][512] bf16
    u16*   qw    = (u16*)(ws + 10747904);       // [2][8][4096][64] bf16 (scale*log2e folded)
    u16*   kw    = (u16*)(ws + 19136512);       // [2][2][4096][64] bf16
    u16*   vt    = (u16*)(ws + 21233664);       // [2][2][64][4096] bf16 (transposed V)
    u16*   ao    = (u16*)(ws + 23330816);       // [8192][512] bf16

    transpose_kernel<<<(512 * 512 + 255) / 256, 256, 0, stream>>>(Wq, WqkvT, 512, 512);
    transpose_kernel<<<(512 * 128 + 255) / 256, 256, 0, stream>>>(Wk, WqkvT + 512 * 512, 512, 128);
    transpose_kernel<<<(512 * 128 + 255) / 256, 256, 0, stream>>>(Wv, WqkvT + 640 * 512, 512, 128);
    transpose_kernel<<<(512 * 512 + 255) / 256, 256, 0, stream>>>(Wo, WoT, 512, 512);
    cvt_kernel<<<(2 * T_SEQ * EMB / 4 + 255) / 256, 256, 0, stream>>>(x, xbf, 2 * T_SEQ * EMB / 4);
    rope_table_kernel<<<(T_SEQ * 32) / 256, 256, 0, stream>>>(cost, sint);

    dim3 gp(64, 6);
    gemm_kernel<1><<<gp, 256, 0, stream>>>(xbf, WqkvT, 512, nullptr, 768,
                                           bq, bk, bv, cost, sint, qw, kw, vt);

    dim3 ga(T_SEQ / 64, 2 * NH);
    attn_kernel<<<ga, 256, 0, stream>>>(qw, kw, vt, ao);

    dim3 go(64, 4);
    gemm_kernel<0><<<go, 256, 0, stream>>>(ao, WoT, 512, out, 512,
                                           nullptr, nullptr, nullptr, nullptr, nullptr,
                                           nullptr, nullptr, nullptr);
}

// Round 5
// 297.493 us; speedup vs baseline: 1.5165x; 1.5165x over previous
//
#include <hip/hip_runtime.h>

typedef unsigned short u16;
typedef __bf16 bf16x8_t __attribute__((ext_vector_type(8)));
typedef float f32x4_t __attribute__((ext_vector_type(4)));

#define T_SEQ 4096
#define EMB 512
#define NH 8
#define NKV 2
#define HD 64

__device__ __forceinline__ float bf2f(u16 h) {
    union { unsigned u; float f; } x; x.u = ((unsigned)h) << 16; return x.f;
}
__device__ __forceinline__ u16 f2bf(float f) {
    union { float f; unsigned u; } x; x.f = f;
    unsigned r = x.u + 0x7FFFu + ((x.u >> 16) & 1u);
    return (u16)(r >> 16);
}

// ------------- weight transpose + cast: W[K][N] (f32) -> WT[N][K] (bf16) -------------
__global__ void transpose_kernel(const float* __restrict__ W, u16* __restrict__ WT,
                                 int K, int N) {
    int i = blockIdx.x * 256 + threadIdx.x;
    if (i < K * N) {
        int n = i / K;
        int k = i - n * K;
        WT[i] = f2bf(W[(size_t)k * N + n]);
    }
}

// ------------- x cast: f32 -> bf16, 4 elems/thread -------------
__global__ void cvt_kernel(const float* __restrict__ in, u16* __restrict__ out, int n4) {
    int i = blockIdx.x * 256 + threadIdx.x;
    if (i < n4) {
        float4 v = *reinterpret_cast<const float4*>(in + (size_t)i * 4);
        u16 o[4] = { f2bf(v.x), f2bf(v.y), f2bf(v.z), f2bf(v.w) };
        *reinterpret_cast<uint2*>(out + (size_t)i * 4) = *reinterpret_cast<uint2*>(o);
    }
}

// ------------- RoPE tables: cos/sin[t][j], j<32, fp32 (double trig ~= np ref) -------------
__global__ void rope_table_kernel(float* __restrict__ cost, float* __restrict__ sint) {
    int i = blockIdx.x * 256 + threadIdx.x;   // T_SEQ*32 total
    int t = i >> 5, j = i & 31;
    double invf = pow(1.0e6, -(double)j / 32.0);
    double ang = (double)t * invf;
    cost[i] = (float)cos(ang);
    sint[i] = (float)sin(ang);
}

// ---------------- GEMM: C[M,N] = A[M,K](bf16) @ Bt[N,K](bf16)^T ----------------
// EPI=0: fp32 store to C.  EPI=1: bias + RoPE + scale-q(incl log2e) + scatter q/k + V transposed.
template <int EPI>
__global__ __launch_bounds__(256)
void gemm_kernel(const u16* __restrict__ A, const u16* __restrict__ Bt, int K,
                 float* __restrict__ C, int N,
                 const float* __restrict__ bq, const float* __restrict__ bk,
                 const float* __restrict__ bv,
                 const float* __restrict__ cost, const float* __restrict__ sint,
                 u16* __restrict__ qw, u16* __restrict__ kw, u16* __restrict__ vt)
{
    __shared__ __align__(16) u16 As[128][72];
    __shared__ __align__(16) u16 Bs[128][72];

    const int tid  = threadIdx.x;
    const int lane = tid & 63, wave = tid >> 6;
    const int wr = wave >> 1, wc = wave & 1;
    const int tm = blockIdx.x, tn = blockIdx.y;
    const int lrow = lane & 15, lgrp = lane >> 4;

    f32x4_t acc[4][4];
#pragma unroll
    for (int i = 0; i < 4; ++i)
#pragma unroll
        for (int j = 0; j < 4; ++j) acc[i][j] = (f32x4_t){0.f, 0.f, 0.f, 0.f};

    for (int k0 = 0; k0 < K; k0 += 64) {
        __syncthreads();
        {
            const int r0 = tid >> 3;
            const int ko = (tid & 7) * 8;
#pragma unroll
            for (int rr = 0; rr < 4; ++rr) {
                int row = r0 + rr * 32;
                uint4 va = *reinterpret_cast<const uint4*>(A + (size_t)(tm * 128 + row) * K + k0 + ko);
                *reinterpret_cast<uint4*>(&As[row][ko]) = va;
                uint4 vb = *reinterpret_cast<const uint4*>(Bt + (size_t)(tn * 128 + row) * K + k0 + ko);
                *reinterpret_cast<uint4*>(&Bs[row][ko]) = vb;
            }
        }
        __syncthreads();
#pragma unroll
        for (int kc = 0; kc < 2; ++kc) {
            bf16x8_t af[4], bf[4];
#pragma unroll
            for (int mb = 0; mb < 4; ++mb)
                af[mb] = *reinterpret_cast<const bf16x8_t*>(&As[wr * 64 + mb * 16 + lrow][kc * 32 + lgrp * 8]);
#pragma unroll
            for (int nb = 0; nb < 4; ++nb)
                bf[nb] = *reinterpret_cast<const bf16x8_t*>(&Bs[wc * 64 + nb * 16 + lrow][kc * 32 + lgrp * 8]);
#pragma unroll
            for (int mb = 0; mb < 4; ++mb)
#pragma unroll
                for (int nb = 0; nb < 4; ++nb)
                    acc[mb][nb] = __builtin_amdgcn_mfma_f32_16x16x32_bf16(af[mb], bf[nb], acc[mb][nb], 0, 0, 0);
        }
    }

    if (EPI == 0) {
#pragma unroll
        for (int mb = 0; mb < 4; ++mb)
#pragma unroll
            for (int nb = 0; nb < 4; ++nb)
#pragma unroll
                for (int r = 0; r < 4; ++r) {
                    int row = tm * 128 + wr * 64 + mb * 16 + lgrp * 4 + r;
                    int col = tn * 128 + wc * 64 + nb * 16 + lrow;
                    C[(size_t)row * N + col] = acc[mb][nb][r];
                }
    } else {
        const float QSC = 0.125f * 1.44269504088896f;   // head_dim^-0.5 * log2(e)
#pragma unroll
        for (int mb = 0; mb < 4; ++mb)
#pragma unroll
            for (int r = 0; r < 4; ++r) {
                int grow = tm * 128 + wr * 64 + mb * 16 + lgrp * 4 + r;
                int b = grow >> 12, t = grow & 4095;
#pragma unroll
                for (int nb = 0; nb < 2; ++nb) {
                    int n = tn * 128 + wc * 64 + nb * 16 + lrow;
                    int j = n & 63;
                    float c0 = acc[mb][nb][r];
                    float c1 = acc[mb][nb + 2][r];
                    if (n < 512) {               // Q (softmax runs in exp2 domain)
                        c0 += bq[n]; c1 += bq[n + 32];
                        float cs = cost[t * 32 + j], sn = sint[t * 32 + j];
                        float r0 = (c0 * cs - c1 * sn) * QSC;
                        float r1 = (c1 * cs + c0 * sn) * QSC;
                        int h = n >> 6;
                        size_t base = ((size_t)(b * NH + h) * T_SEQ + t) * HD;
                        qw[base + j]      = f2bf(r0);
                        qw[base + j + 32] = f2bf(r1);
                    } else if (n < 640) {        // K
                        int nn = n - 512;
                        c0 += bk[nn]; c1 += bk[nn + 32];
                        float cs = cost[t * 32 + j], sn = sint[t * 32 + j];
                        float r0 = c0 * cs - c1 * sn;
                        float r1 = c1 * cs + c0 * sn;
                        int hk2 = nn >> 6;
                        size_t base = ((size_t)(b * NKV + hk2) * T_SEQ + t) * HD;
                        kw[base + j]      = f2bf(r0);
                        kw[base + j + 32] = f2bf(r1);
                    } else {                     // V -> transposed vt[b][hk][d][t]
                        int nn = n - 640;
                        c0 += bv[nn]; c1 += bv[nn + 32];
                        int hv = nn >> 6;
                        size_t base = (size_t)(b * NKV + hv) * HD * T_SEQ;
                        vt[base + (size_t)j * T_SEQ + t]        = f2bf(c0);
                        vt[base + (size_t)(j + 32) * T_SEQ + t] = f2bf(c1);
                    }
                }
            }
    }
}

// ---------------- causal flash attention: QBLK=128, staged+prefetched, balanced ----------------
// grid: (B*NH=16, 32). qt = j<16 ? 31-j : j-16  -> co-resident block pair has 64-2j & 2j+2 iters.
// 4 waves x 32 q-rows (2 sub-blocks of 16). K and V(transposed) staged via identical
// XOR-swizzled vector copies; double-buffered; early-issue/late-write prefetch; 1 barrier/iter.
__global__ __launch_bounds__(256)
void attn_kernel(const u16* __restrict__ qw, const u16* __restrict__ kw,
                 const u16* __restrict__ vt, u16* __restrict__ ao)
{
    __shared__ __align__(16) u16 Ks[2][64][64];
    __shared__ __align__(16) u16 Vs[2][64][64];
    __shared__ __align__(16) __bf16 Ps[4][32][68];

    const int jj = blockIdx.y;
    const int qt = (jj < 16) ? (31 - jj) : (jj - 16);
    const int hdix = blockIdx.x;
    const int b = hdix >> 3, h = hdix & 7, hk = h >> 2;
    const int tid = threadIdx.x, lane = tid & 63, wave = tid >> 6;
    const int lrow = lane & 15, lgrp = lane >> 4;

    const u16* qbase  = qw + ((size_t)(b * NH + h) * T_SEQ + qt * 128) * HD;
    const u16* kbase  = kw + (size_t)(b * NKV + hk) * T_SEQ * HD;
    const u16* vtbase = vt + (size_t)(b * NKV + hk) * HD * T_SEQ;

    const int nkt = 2 * qt + 2;          // number of 64-wide k-tiles
    const int ss = tid >> 3;             // 0..31: row (K) / d-row (V)
    const int sb = tid & 7;              // 16B block within 64-elem row

    bf16x8_t qf[2][2];
#pragma unroll
    for (int mq = 0; mq < 2; ++mq)
#pragma unroll
        for (int kc = 0; kc < 2; ++kc)
            qf[mq][kc] = *reinterpret_cast<const bf16x8_t*>(
                qbase + (mq * 64 + wave * 16 + lrow) * HD + kc * 32 + lgrp * 8);

    float m[2][4], l[2][4];
    f32x4_t o[2][4];
#pragma unroll
    for (int mq = 0; mq < 2; ++mq)
#pragma unroll
        for (int r = 0; r < 4; ++r) { m[mq][r] = -1e30f; l[mq][r] = 0.f; }
#pragma unroll
    for (int mq = 0; mq < 2; ++mq)
#pragma unroll
        for (int d = 0; d < 4; ++d) o[mq][d] = (f32x4_t){0.f, 0.f, 0.f, 0.f};

    uint4 kr[2], vr[2];

    // ---- prologue: stage tile 0 ----
#pragma unroll
    for (int rr = 0; rr < 2; ++rr) {
        int s = ss + 32 * rr;
        kr[rr] = *reinterpret_cast<const uint4*>(kbase + (size_t)s * HD + sb * 8);
        vr[rr] = *reinterpret_cast<const uint4*>(vtbase + (size_t)s * T_SEQ + sb * 8);
    }
#pragma unroll
    for (int rr = 0; rr < 2; ++rr) {
        int s = ss + 32 * rr;
        *reinterpret_cast<uint4*>(&Ks[0][s][(sb ^ (s & 7)) << 3]) = kr[rr];
        *reinterpret_cast<uint4*>(&Vs[0][s][(sb ^ (s & 7)) << 3]) = vr[rr];
    }
    __syncthreads();

    for (int kt = 0; kt < nkt; ++kt) {
        const int cur = kt & 1;
        const bool pre = (kt + 1 < nkt);

        // ---- issue next tile's global loads early ----
        if (pre) {
#pragma unroll
            for (int rr = 0; rr < 2; ++rr) {
                int s = ss + 32 * rr;
                kr[rr] = *reinterpret_cast<const uint4*>(kbase + (size_t)((kt + 1) * 64 + s) * HD + sb * 8);
                vr[rr] = *reinterpret_cast<const uint4*>(vtbase + (size_t)s * T_SEQ + (kt + 1) * 64 + sb * 8);
            }
        }

#pragma unroll
        for (int mq = 0; mq < 2; ++mq) {
            if (kt > 2 * qt + mq) continue;          // tile fully beyond diagonal for this sub-block

            // ---- S = q @ k^T ----
            f32x4_t sacc[4];
#pragma unroll
            for (int kb = 0; kb < 4; ++kb) sacc[kb] = (f32x4_t){0.f, 0.f, 0.f, 0.f};
            __builtin_amdgcn_s_setprio(1);
#pragma unroll
            for (int kc = 0; kc < 2; ++kc)
#pragma unroll
                for (int kb = 0; kb < 4; ++kb) {
                    bf16x8_t kf = *reinterpret_cast<const bf16x8_t*>(
                        &Ks[cur][kb * 16 + lrow][(((kc << 2) + lgrp) ^ (lrow & 7)) << 3]);
                    sacc[kb] = __builtin_amdgcn_mfma_f32_16x16x32_bf16(qf[mq][kc], kf, sacc[kb], 0, 0, 0);
                }
            __builtin_amdgcn_s_setprio(0);

            if (kt == 2 * qt + mq) {                 // diagonal tile for this sub-block
#pragma unroll
                for (int kb = 0; kb < 4; ++kb)
#pragma unroll
                    for (int r = 0; r < 4; ++r) {
                        int qr = wave * 16 + lgrp * 4 + r;
                        int kc2 = kb * 16 + lrow;
                        if (kc2 > qr) sacc[kb][r] = -1e30f;
                    }
            }

            // ---- online softmax in exp2 domain ----
            float al[4];
#pragma unroll
            for (int r = 0; r < 4; ++r) {
                float v = fmaxf(fmaxf(sacc[0][r], sacc[1][r]), fmaxf(sacc[2][r], sacc[3][r]));
#pragma unroll
                for (int off = 1; off < 16; off <<= 1) v = fmaxf(v, __shfl_xor(v, off));
                float mn = fmaxf(m[mq][r], v);
                al[r] = exp2f(m[mq][r] - mn);
                m[mq][r] = mn;
            }
#pragma unroll
            for (int kb = 0; kb < 4; ++kb)
#pragma unroll
                for (int r = 0; r < 4; ++r) sacc[kb][r] = exp2f(sacc[kb][r] - m[mq][r]);
#pragma unroll
            for (int r = 0; r < 4; ++r) {
                float v = sacc[0][r] + sacc[1][r] + sacc[2][r] + sacc[3][r];
#pragma unroll
                for (int off = 1; off < 16; off <<= 1) v += __shfl_xor(v, off);
                l[mq][r] = l[mq][r] * al[r] + v;
            }
#pragma unroll
            for (int d = 0; d < 4; ++d)
#pragma unroll
                for (int r = 0; r < 4; ++r) o[mq][d][r] *= al[r];

            // ---- P via wave-private LDS (no barrier) ----
#pragma unroll
            for (int kb = 0; kb < 4; ++kb)
#pragma unroll
                for (int r = 0; r < 4; ++r)
                    Ps[wave][mq * 16 + lgrp * 4 + r][kb * 16 + lrow] = (__bf16)sacc[kb][r];

            // ---- O += P @ V ----
            __builtin_amdgcn_s_setprio(1);
#pragma unroll
            for (int kc = 0; kc < 2; ++kc) {
                bf16x8_t pf = *reinterpret_cast<const bf16x8_t*>(&Ps[wave][mq * 16 + lrow][kc * 32 + lgrp * 8]);
#pragma unroll
                for (int d = 0; d < 4; ++d) {
                    bf16x8_t vf = *reinterpret_cast<const bf16x8_t*>(
                        &Vs[cur][d * 16 + lrow][(((kc << 2) + lgrp) ^ (lrow & 7)) << 3]);
                    o[mq][d] = __builtin_amdgcn_mfma_f32_16x16x32_bf16(pf, vf, o[mq][d], 0, 0, 0);
                }
            }
            __builtin_amdgcn_s_setprio(0);
        }

        // ---- write staged next tile, single barrier ----
        if (pre) {
            const int nxt = cur ^ 1;
#pragma unroll
            for (int rr = 0; rr < 2; ++rr) {
                int s = ss + 32 * rr;
                *reinterpret_cast<uint4*>(&Ks[nxt][s][(sb ^ (s & 7)) << 3]) = kr[rr];
                *reinterpret_cast<uint4*>(&Vs[nxt][s][(sb ^ (s & 7)) << 3]) = vr[rr];
            }
            __syncthreads();
        }
    }

    // epilogue: normalize and store [B,T,H*D] (bf16)
#pragma unroll
    for (int mq = 0; mq < 2; ++mq)
#pragma unroll
        for (int d = 0; d < 4; ++d)
#pragma unroll
            for (int r = 0; r < 4; ++r) {
                int t = qt * 128 + mq * 64 + wave * 16 + lgrp * 4 + r;
                float inv = 1.0f / l[mq][r];
                ao[((size_t)(b * T_SEQ) + t) * EMB + h * HD + d * 16 + lrow] = f2bf(o[mq][d][r] * inv);
            }
}

// ---------------- launch ----------------
extern "C" void kernel_launch(void* const* d_in, const int* in_sizes, int n_in,
                              void* d_out, int out_size, void* d_ws, size_t ws_size,
                              hipStream_t stream)
{
    const float* x  = (const float*)d_in[0];
    const float* Wq = (const float*)d_in[1];
    const float* bq = (const float*)d_in[2];
    const float* Wk = (const float*)d_in[3];
    const float* bk = (const float*)d_in[4];
    const float* Wv = (const float*)d_in[5];
    const float* bv = (const float*)d_in[6];
    const float* Wo = (const float*)d_in[7];
    float* out = (float*)d_out;

    char* ws = (char*)d_ws;
    u16*   WqkvT = (u16*)(ws);                  // [768][512] bf16
    u16*   WoT   = (u16*)(ws + 786432);         // [512][512] bf16
    float* cost  = (float*)(ws + 1310720);      // [4096][32] f32
    float* sint  = (float*)(ws + 1835008);      // [4096][32] f32
    u16*   xbf   = (u16*)(ws + 2359296);        // [8192][512] bf16
    u16*   qw    = (u16*)(ws + 10747904);       // [2][8][4096][64] bf16 (scale*log2e folded)
    u16*   kw    = (u16*)(ws + 19136512);       // [2][2][4096][64] bf16
    u16*   vt    = (u16*)(ws + 21233664);       // [2][2][64][4096] bf16 (transposed V)
    u16*   ao    = (u16*)(ws + 23330816);       // [8192][512] bf16

    transpose_kernel<<<(512 * 512 + 255) / 256, 256, 0, stream>>>(Wq, WqkvT, 512, 512);
    transpose_kernel<<<(512 * 128 + 255) / 256, 256, 0, stream>>>(Wk, WqkvT + 512 * 512, 512, 128);
    transpose_kernel<<<(512 * 128 + 255) / 256, 256, 0, stream>>>(Wv, WqkvT + 640 * 512, 512, 128);
    transpose_kernel<<<(512 * 512 + 255) / 256, 256, 0, stream>>>(Wo, WoT, 512, 512);
    cvt_kernel<<<(2 * T_SEQ * EMB / 4 + 255) / 256, 256, 0, stream>>>(x, xbf, 2 * T_SEQ * EMB / 4);
    rope_table_kernel<<<(T_SEQ * 32) / 256, 256, 0, stream>>>(cost, sint);

    dim3 gp(64, 6);
    gemm_kernel<1><<<gp, 256, 0, stream>>>(xbf, WqkvT, 512, nullptr, 768,
                                           bq, bk, bv, cost, sint, qw, kw, vt);

    dim3 ga(2 * NH, 32);   // x = batch*head, y = balanced qt index
    attn_kernel<<<ga, 256, 0, stream>>>(qw, kw, vt, ao);

    dim3 go(64, 4);
    gemm_kernel<0><<<go, 256, 0, stream>>>(ao, WoT, 512, out, 512,
                                           nullptr, nullptr, nullptr, nullptr, nullptr,
                                           nullptr, nullptr, nullptr);
}

// Round 6
// 195.244 us; speedup vs baseline: 2.3107x; 1.5237x over previous
//
#include <hip/hip_runtime.h>

typedef unsigned short u16;
typedef unsigned int u32;
typedef __bf16 bf16x8_t __attribute__((ext_vector_type(8)));
typedef float f32x4_t __attribute__((ext_vector_type(4)));
typedef float f32x16_t __attribute__((ext_vector_type(16)));

#define T_SEQ 4096
#define EMB 512
#define NH 8
#define NKV 2
#define HD 64

__device__ __forceinline__ float bf2f(u16 h) {
    union { unsigned u; float f; } x; x.u = ((unsigned)h) << 16; return x.f;
}
__device__ __forceinline__ u16 f2bf(float f) {
    union { float f; unsigned u; } x; x.f = f;
    unsigned r = x.u + 0x7FFFu + ((x.u >> 16) & 1u);
    return (u16)(r >> 16);
}

// ------------- weight transpose + cast: W[K][N] (f32) -> WT[N][K] (bf16) -------------
__global__ void transpose_kernel(const float* __restrict__ W, u16* __restrict__ WT,
                                 int K, int N) {
    int i = blockIdx.x * 256 + threadIdx.x;
    if (i < K * N) {
        int n = i / K;
        int k = i - n * K;
        WT[i] = f2bf(W[(size_t)k * N + n]);
    }
}

// ------------- x cast: f32 -> bf16, 4 elems/thread -------------
__global__ void cvt_kernel(const float* __restrict__ in, u16* __restrict__ out, int n4) {
    int i = blockIdx.x * 256 + threadIdx.x;
    if (i < n4) {
        float4 v = *reinterpret_cast<const float4*>(in + (size_t)i * 4);
        u16 o[4] = { f2bf(v.x), f2bf(v.y), f2bf(v.z), f2bf(v.w) };
        *reinterpret_cast<uint2*>(out + (size_t)i * 4) = *reinterpret_cast<uint2*>(o);
    }
}

// ------------- RoPE tables -------------
__global__ void rope_table_kernel(float* __restrict__ cost, float* __restrict__ sint) {
    int i = blockIdx.x * 256 + threadIdx.x;   // T_SEQ*32 total
    int t = i >> 5, j = i & 31;
    double invf = pow(1.0e6, -(double)j / 32.0);
    double ang = (double)t * invf;
    cost[i] = (float)cos(ang);
    sint[i] = (float)sin(ang);
}

// ---------------- GEMM: C[M,N] = A[M,K](bf16) @ Bt[N,K](bf16)^T ----------------
template <int EPI>
__global__ __launch_bounds__(256)
void gemm_kernel(const u16* __restrict__ A, const u16* __restrict__ Bt, int K,
                 float* __restrict__ C, int N,
                 const float* __restrict__ bq, const float* __restrict__ bk,
                 const float* __restrict__ bv,
                 const float* __restrict__ cost, const float* __restrict__ sint,
                 u16* __restrict__ qw, u16* __restrict__ kw, u16* __restrict__ vt)
{
    __shared__ __align__(16) u16 As[128][72];
    __shared__ __align__(16) u16 Bs[128][72];

    const int tid  = threadIdx.x;
    const int lane = tid & 63, wave = tid >> 6;
    const int wr = wave >> 1, wc = wave & 1;
    const int tm = blockIdx.x, tn = blockIdx.y;
    const int lrow = lane & 15, lgrp = lane >> 4;

    f32x4_t acc[4][4];
#pragma unroll
    for (int i = 0; i < 4; ++i)
#pragma unroll
        for (int j = 0; j < 4; ++j) acc[i][j] = (f32x4_t){0.f, 0.f, 0.f, 0.f};

    for (int k0 = 0; k0 < K; k0 += 64) {
        __syncthreads();
        {
            const int r0 = tid >> 3;
            const int ko = (tid & 7) * 8;
#pragma unroll
            for (int rr = 0; rr < 4; ++rr) {
                int row = r0 + rr * 32;
                uint4 va = *reinterpret_cast<const uint4*>(A + (size_t)(tm * 128 + row) * K + k0 + ko);
                *reinterpret_cast<uint4*>(&As[row][ko]) = va;
                uint4 vb = *reinterpret_cast<const uint4*>(Bt + (size_t)(tn * 128 + row) * K + k0 + ko);
                *reinterpret_cast<uint4*>(&Bs[row][ko]) = vb;
            }
        }
        __syncthreads();
#pragma unroll
        for (int kc = 0; kc < 2; ++kc) {
            bf16x8_t af[4], bf[4];
#pragma unroll
            for (int mb = 0; mb < 4; ++mb)
                af[mb] = *reinterpret_cast<const bf16x8_t*>(&As[wr * 64 + mb * 16 + lrow][kc * 32 + lgrp * 8]);
#pragma unroll
            for (int nb = 0; nb < 4; ++nb)
                bf[nb] = *reinterpret_cast<const bf16x8_t*>(&Bs[wc * 64 + nb * 16 + lrow][kc * 32 + lgrp * 8]);
#pragma unroll
            for (int mb = 0; mb < 4; ++mb)
#pragma unroll
                for (int nb = 0; nb < 4; ++nb)
                    acc[mb][nb] = __builtin_amdgcn_mfma_f32_16x16x32_bf16(af[mb], bf[nb], acc[mb][nb], 0, 0, 0);
        }
    }

    if (EPI == 0) {
#pragma unroll
        for (int mb = 0; mb < 4; ++mb)
#pragma unroll
            for (int nb = 0; nb < 4; ++nb)
#pragma unroll
                for (int r = 0; r < 4; ++r) {
                    int row = tm * 128 + wr * 64 + mb * 16 + lgrp * 4 + r;
                    int col = tn * 128 + wc * 64 + nb * 16 + lrow;
                    C[(size_t)row * N + col] = acc[mb][nb][r];
                }
    } else {
        const float QSC = 0.125f * 1.44269504088896f;   // head_dim^-0.5 * log2(e)
#pragma unroll
        for (int mb = 0; mb < 4; ++mb)
#pragma unroll
            for (int r = 0; r < 4; ++r) {
                int grow = tm * 128 + wr * 64 + mb * 16 + lgrp * 4 + r;
                int b = grow >> 12, t = grow & 4095;
#pragma unroll
                for (int nb = 0; nb < 2; ++nb) {
                    int n = tn * 128 + wc * 64 + nb * 16 + lrow;
                    int j = n & 63;
                    float c0 = acc[mb][nb][r];
                    float c1 = acc[mb][nb + 2][r];
                    if (n < 512) {               // Q (softmax runs in exp2 domain)
                        c0 += bq[n]; c1 += bq[n + 32];
                        float cs = cost[t * 32 + j], sn = sint[t * 32 + j];
                        float r0 = (c0 * cs - c1 * sn) * QSC;
                        float r1 = (c1 * cs + c0 * sn) * QSC;
                        int h = n >> 6;
                        size_t base = ((size_t)(b * NH + h) * T_SEQ + t) * HD;
                        qw[base + j]      = f2bf(r0);
                        qw[base + j + 32] = f2bf(r1);
                    } else if (n < 640) {        // K
                        int nn = n - 512;
                        c0 += bk[nn]; c1 += bk[nn + 32];
                        float cs = cost[t * 32 + j], sn = sint[t * 32 + j];
                        float r0 = c0 * cs - c1 * sn;
                        float r1 = c1 * cs + c0 * sn;
                        int hk2 = nn >> 6;
                        size_t base = ((size_t)(b * NKV + hk2) * T_SEQ + t) * HD;
                        kw[base + j]      = f2bf(r0);
                        kw[base + j + 32] = f2bf(r1);
                    } else {                     // V -> transposed vt[b][hk][d][t]
                        int nn = n - 640;
                        c0 += bv[nn]; c1 += bv[nn + 32];
                        int hv = nn >> 6;
                        size_t base = (size_t)(b * NKV + hv) * HD * T_SEQ;
                        vt[base + (size_t)j * T_SEQ + t]        = f2bf(c0);
                        vt[base + (size_t)(j + 32) * T_SEQ + t] = f2bf(c1);
                    }
                }
            }
    }
}

// ---------------- causal flash attention: swapped-QK 32x32 MFMA, in-register softmax ----------------
// grid (16 bh, 16 j). Block = 4 waves x 32 q-rows (QBLK=128); processes q-tiles {31-j, j}
// sequentially -> every block exactly 66 k-tile iterations (perfect balance, 1 block/CU).
//
// Swapped QK^T: sacc = mfma(K_frag, Q_frag) = S^T tile; lane holds q = lane&31,
// kv = (reg&3)+8*(reg>>2)+4*hi (+32 for second kv half). Row reduce = in-lane + 1 shfl_xor(32).
// P repacked in-register to PV A-operand via v_cvt_pk_bf16_f32 + shfl_xor(32)
// (verified: frag s, lane hi needs kv 16s+8hi+0..7; own pack c=2s+hi supplies words 2hi,2hi+1,
//  partner's same-c pack supplies the complementary pair).
// Defer-max (THR=8, exp2 domain): O-rescale (16-shfl gather, q lives in regs) runs rarely.
__global__ __launch_bounds__(256)
void attn_kernel(const u16* __restrict__ qw, const u16* __restrict__ kw,
                 const u16* __restrict__ vt, u16* __restrict__ ao)
{
    __shared__ __align__(16) u16 Ks[2][64][64];   // [buf][kv][d], 16B-granule XOR swizzle
    __shared__ __align__(16) u16 Vs[2][64][64];   // [buf][d][kv], same swizzle

    const int hdix = blockIdx.x;
    const int b = hdix >> 3, h = hdix & 7, hk = h >> 2;
    const int j = blockIdx.y;
    const int tid = threadIdx.x, lane = tid & 63, wave = tid >> 6;
    const int lid = lane & 31, hi = lane >> 5;

    const u16* kbase  = kw + (size_t)(b * NKV + hk) * T_SEQ * HD;
    const u16* vtbase = vt + (size_t)(b * NKV + hk) * HD * T_SEQ;

    const int ss = tid >> 3;                 // staging row 0..31 (and +32)
    const int sg = tid & 7;                  // staging granule
    const int swz = (sg ^ (ss & 7)) << 3;    // swizzled column offset (elems)

    for (int ph = 0; ph < 2; ++ph) {
        const int qt = ph ? j : (31 - j);
        const int q0 = qt * 128 + wave * 32;
        const int nkt = 2 * qt + 2;

        // Q fragments (B-operand): lane holds Q[q0+lid][16t + 8hi + 0..7]
        bf16x8_t qf[4];
        {
            const u16* qrow = qw + ((size_t)(b * NH + h) * T_SEQ + q0 + lid) * HD + 8 * hi;
#pragma unroll
            for (int t = 0; t < 4; ++t)
                qf[t] = *reinterpret_cast<const bf16x8_t*>(qrow + 16 * t);
        }

        f32x16_t o0, o1;
#pragma unroll
        for (int i = 0; i < 16; ++i) { o0[i] = 0.f; o1[i] = 0.f; }
        float m = -1e4f, l = 0.f;            // finite init: masked rows stay exp2(-1e30-m)=0

        // prologue: stage tile 0 into buffer 0
        {
            uint4 ka = *reinterpret_cast<const uint4*>(kbase + (size_t)ss * HD + sg * 8);
            uint4 kb2 = *reinterpret_cast<const uint4*>(kbase + (size_t)(ss + 32) * HD + sg * 8);
            uint4 va = *reinterpret_cast<const uint4*>(vtbase + (size_t)ss * T_SEQ + sg * 8);
            uint4 vb2 = *reinterpret_cast<const uint4*>(vtbase + (size_t)(ss + 32) * T_SEQ + sg * 8);
            *reinterpret_cast<uint4*>(&Ks[0][ss][swz]) = ka;
            *reinterpret_cast<uint4*>(&Ks[0][ss + 32][swz]) = kb2;
            *reinterpret_cast<uint4*>(&Vs[0][ss][swz]) = va;
            *reinterpret_cast<uint4*>(&Vs[0][ss + 32][swz]) = vb2;
        }
        __syncthreads();

        for (int kt = 0; kt < nkt; ++kt) {
            const int cur = kt & 1, nxt = cur ^ 1;
            const bool pre = (kt + 1 < nkt);

            // early-issue next tile's global loads (consumed after compute)
            uint4 kr0, kr1, vr0, vr1;
            if (pre) {
                const int s2 = (kt + 1) * 64;
                kr0 = *reinterpret_cast<const uint4*>(kbase + (size_t)(s2 + ss) * HD + sg * 8);
                kr1 = *reinterpret_cast<const uint4*>(kbase + (size_t)(s2 + ss + 32) * HD + sg * 8);
                vr0 = *reinterpret_cast<const uint4*>(vtbase + (size_t)ss * T_SEQ + s2 + sg * 8);
                vr1 = *reinterpret_cast<const uint4*>(vtbase + (size_t)(ss + 32) * T_SEQ + s2 + sg * 8);
            }

            if (kt * 64 <= q0 + 31) {        // wave has visible kv in this tile
                // ---- S^T = K_tile . Q^T ----
                f32x16_t s0, s1;
#pragma unroll
                for (int i = 0; i < 16; ++i) { s0[i] = 0.f; s1[i] = 0.f; }
                __builtin_amdgcn_s_setprio(1);
#pragma unroll
                for (int t = 0; t < 4; ++t) {
                    const int g = ((2 * t + hi) ^ (lid & 7)) << 3;
                    bf16x8_t ka = *reinterpret_cast<const bf16x8_t*>(&Ks[cur][lid][g]);
                    bf16x8_t kb2 = *reinterpret_cast<const bf16x8_t*>(&Ks[cur][lid + 32][g]);
                    s0 = __builtin_amdgcn_mfma_f32_32x32x16_bf16(ka, qf[t], s0, 0, 0, 0);
                    s1 = __builtin_amdgcn_mfma_f32_32x32x16_bf16(kb2, qf[t], s1, 0, 0, 0);
                }
                __builtin_amdgcn_s_setprio(0);

                // ---- causal mask (diagonal tiles only) ----
                if (kt * 64 + 63 > q0) {
                    const int qg = q0 + lid;
                    const int kvb = kt * 64 + 4 * hi;
#pragma unroll
                    for (int r = 0; r < 16; ++r) {
                        int kv = kvb + (r & 3) + 8 * (r >> 2);
                        if (kv > qg)      s0[r] = -1e30f;
                        if (kv + 32 > qg) s1[r] = -1e30f;
                    }
                }

                // ---- online softmax, exp2 domain, row = lane-local ----
                float smax = s0[0];
#pragma unroll
                for (int r = 1; r < 16; ++r) smax = fmaxf(smax, s0[r]);
#pragma unroll
                for (int r = 0; r < 16; ++r) smax = fmaxf(smax, s1[r]);
                smax = fmaxf(smax, __shfl_xor(smax, 32));

                if (__any(smax > m + 8.0f)) {    // defer-max: rescale rarely
                    float mn = fmaxf(m, smax);
                    float al = exp2f(m - mn);
                    m = mn;
                    l *= al;
#pragma unroll
                    for (int r = 0; r < 16; ++r) {
                        float ar = __shfl(al, (r & 3) + 8 * (r >> 2) + 4 * hi);
                        o0[r] *= ar;
                        o1[r] *= ar;
                    }
                }

#pragma unroll
                for (int r = 0; r < 16; ++r) s0[r] = exp2f(s0[r] - m);
#pragma unroll
                for (int r = 0; r < 16; ++r) s1[r] = exp2f(s1[r] - m);

                float rs = 0.f;
#pragma unroll
                for (int r = 0; r < 16; ++r) rs += s0[r] + s1[r];
                rs += __shfl_xor(rs, 32);
                l += rs;

                // ---- in-register P repack -> PV A-fragments ----
                bf16x8_t pa[4];
                {
                    u32 pw[8], pe[8];
                    uint4 f0, f1;
#pragma unroll
                    for (int c = 0; c < 4; ++c) {
                        asm("v_cvt_pk_bf16_f32 %0, %1, %2" : "=v"(pw[2 * c])     : "v"(s0[4 * c]),     "v"(s0[4 * c + 1]));
                        asm("v_cvt_pk_bf16_f32 %0, %1, %2" : "=v"(pw[2 * c + 1]) : "v"(s0[4 * c + 2]), "v"(s0[4 * c + 3]));
                    }
#pragma unroll
                    for (int i = 0; i < 8; ++i) pe[i] = (u32)__shfl_xor((int)pw[i], 32);
                    f0.x = hi ? pe[2] : pw[0]; f0.y = hi ? pe[3] : pw[1];
                    f0.z = hi ? pw[2] : pe[0]; f0.w = hi ? pw[3] : pe[1];
                    f1.x = hi ? pe[6] : pw[4]; f1.y = hi ? pe[7] : pw[5];
                    f1.z = hi ? pw[6] : pe[4]; f1.w = hi ? pw[7] : pe[5];
                    pa[0] = __builtin_bit_cast(bf16x8_t, f0);
                    pa[1] = __builtin_bit_cast(bf16x8_t, f1);
#pragma unroll
                    for (int c = 0; c < 4; ++c) {
                        asm("v_cvt_pk_bf16_f32 %0, %1, %2" : "=v"(pw[2 * c])     : "v"(s1[4 * c]),     "v"(s1[4 * c + 1]));
                        asm("v_cvt_pk_bf16_f32 %0, %1, %2" : "=v"(pw[2 * c + 1]) : "v"(s1[4 * c + 2]), "v"(s1[4 * c + 3]));
                    }
#pragma unroll
                    for (int i = 0; i < 8; ++i) pe[i] = (u32)__shfl_xor((int)pw[i], 32);
                    f0.x = hi ? pe[2] : pw[0]; f0.y = hi ? pe[3] : pw[1];
                    f0.z = hi ? pw[2] : pe[0]; f0.w = hi ? pw[3] : pe[1];
                    f1.x = hi ? pe[6] : pw[4]; f1.y = hi ? pe[7] : pw[5];
                    f1.z = hi ? pw[6] : pe[4]; f1.w = hi ? pw[7] : pe[5];
                    pa[2] = __builtin_bit_cast(bf16x8_t, f0);
                    pa[3] = __builtin_bit_cast(bf16x8_t, f1);
                }

                // ---- O += P @ V ----
                __builtin_amdgcn_s_setprio(1);
#pragma unroll
                for (int s = 0; s < 4; ++s) {
                    const int g = ((2 * s + hi) ^ (lid & 7)) << 3;
                    bf16x8_t v0f = *reinterpret_cast<const bf16x8_t*>(&Vs[cur][lid][g]);
                    bf16x8_t v1f = *reinterpret_cast<const bf16x8_t*>(&Vs[cur][lid + 32][g]);
                    o0 = __builtin_amdgcn_mfma_f32_32x32x16_bf16(pa[s], v0f, o0, 0, 0, 0);
                    o1 = __builtin_amdgcn_mfma_f32_32x32x16_bf16(pa[s], v1f, o1, 0, 0, 0);
                }
                __builtin_amdgcn_s_setprio(0);
            }

            // late write of prefetched tile, single barrier
            if (pre) {
                *reinterpret_cast<uint4*>(&Ks[nxt][ss][swz]) = kr0;
                *reinterpret_cast<uint4*>(&Ks[nxt][ss + 32][swz]) = kr1;
                *reinterpret_cast<uint4*>(&Vs[nxt][ss][swz]) = vr0;
                *reinterpret_cast<uint4*>(&Vs[nxt][ss + 32][swz]) = vr1;
            }
            __syncthreads();
        }

        // ---- epilogue: normalize (gather 1/l to reg-q) and store [B,T,H*D] ----
        float inv = 1.0f / l;
#pragma unroll
        for (int r = 0; r < 16; ++r) {
            int qr = (r & 3) + 8 * (r >> 2) + 4 * hi;
            float ir = __shfl(inv, qr);
            size_t base = ((size_t)(b * T_SEQ) + q0 + qr) * EMB + h * HD;
            ao[base + lid]      = f2bf(o0[r] * ir);
            ao[base + lid + 32] = f2bf(o1[r] * ir);
        }
    }
}

// ---------------- launch ----------------
extern "C" void kernel_launch(void* const* d_in, const int* in_sizes, int n_in,
                              void* d_out, int out_size, void* d_ws, size_t ws_size,
                              hipStream_t stream)
{
    const float* x  = (const float*)d_in[0];
    const float* Wq = (const float*)d_in[1];
    const float* bq = (const float*)d_in[2];
    const float* Wk = (const float*)d_in[3];
    const float* bk = (const float*)d_in[4];
    const float* Wv = (const float*)d_in[5];
    const float* bv = (const float*)d_in[6];
    const float* Wo = (const float*)d_in[7];
    float* out = (float*)d_out;

    char* ws = (char*)d_ws;
    u16*   WqkvT = (u16*)(ws);                  // [768][512] bf16
    u16*   WoT   = (u16*)(ws + 786432);         // [512][512] bf16
    float* cost  = (float*)(ws + 1310720);      // [4096][32] f32
    float* sint  = (float*)(ws + 1835008);      // [4096][32] f32
    u16*   xbf   = (u16*)(ws + 2359296);        // [8192][512] bf16
    u16*   qw    = (u16*)(ws + 10747904);       // [2][8][4096][64] bf16 (scale*log2e folded)
    u16*   kw    = (u16*)(ws + 19136512);       // [2][2][4096][64] bf16
    u16*   vt    = (u16*)(ws + 21233664);       // [2][2][64][4096] bf16 (transposed V)
    u16*   ao    = (u16*)(ws + 23330816);       // [8192][512] bf16

    transpose_kernel<<<(512 * 512 + 255) / 256, 256, 0, stream>>>(Wq, WqkvT, 512, 512);
    transpose_kernel<<<(512 * 128 + 255) / 256, 256, 0, stream>>>(Wk, WqkvT + 512 * 512, 512, 128);
    transpose_kernel<<<(512 * 128 + 255) / 256, 256, 0, stream>>>(Wv, WqkvT + 640 * 512, 512, 128);
    transpose_kernel<<<(512 * 512 + 255) / 256, 256, 0, stream>>>(Wo, WoT, 512, 512);
    cvt_kernel<<<(2 * T_SEQ * EMB / 4 + 255) / 256, 256, 0, stream>>>(x, xbf, 2 * T_SEQ * EMB / 4);
    rope_table_kernel<<<(T_SEQ * 32) / 256, 256, 0, stream>>>(cost, sint);

    dim3 gp(64, 6);
    gemm_kernel<1><<<gp, 256, 0, stream>>>(xbf, WqkvT, 512, nullptr, 768,
                                           bq, bk, bv, cost, sint, qw, kw, vt);

    dim3 ga(2 * NH, 16);   // x = batch*head, y = balanced q-tile pair {31-j, j}
    attn_kernel<<<ga, 256, 0, stream>>>(qw, kw, vt, ao);

    dim3 go(64, 4);
    gemm_kernel<0><<<go, 256, 0, stream>>>(ao, WoT, 512, out, 512,
                                           nullptr, nullptr, nullptr, nullptr, nullptr,
                                           nullptr, nullptr, nullptr);
}